// Round 4
// baseline (1228.325 us; speedup 1.0000x reference)
//
#include <hip/hip_runtime.h>

// deltaLayer: out[b,c,i,j] = |l[b,c,j] - r[b,c,i]|
// BS=2, CHAN=128, H=1, W=900 -> out is (2,128,900,900) fp32 = 829.4 MB.
//
// R1: occupancy 16->32 waves/CU + unroll-5: +15%. Not latency-bound.
// R2: NT -> plain stores: -2%. NT exonerated.
// R3: zero-baggage row-sweep (no LDS, no div, s_load rv): -2.5% (WORSE).
//     => limiter is NOT in the instruction stream. 3 mismatched theories.
// R4: CALIBRATION ROUND. Kernel counters have never been visible (fills
//     monopolize top-5). Run the identical R2 store sweep 5x in one
//     dispatch (idempotent; absmax unchanged) so the dispatch is >660us
//     and ranks #1, exposing WRITE_SIZE / FETCH_SIZE / hbm_gbps /
//     VALUBusy / Occupancy for this exact store pattern.
//     Decision rules pre-committed in the journal:
//       BW>=5.5 TB/s -> 1x kernel was already rooflined, revert to R2.
//       BW~3 TB/s, WRITE=5x, FETCH small -> DRAM-locality sweep next.
//       FETCH ~= WRITE -> write-allocate RMW, fix store alignment next.

#define BS    2
#define CHAN  128
#define W     900
#define W4    225                // W/4 float4 per output row
#define TILE4 (W * W4)           // 202500 float4 per (b,c) tile
#define SPLIT 16                 // blocks per (b,c) tile
#define PART  12800              // 50*256 float4 per full part
#define NFULL 50                 // iterations/thread in full parts
#define PASSES 5                 // calibration: repeat identical writes

typedef float v4f __attribute__((ext_vector_type(4)));

__global__ __launch_bounds__(256, 8)
void deltaLayer_57294863728910_kernel(const float* __restrict__ l,
                                      const float* __restrict__ r,
                                      float* __restrict__ out) {
    __shared__ float sl[W];
    __shared__ float sr[W];

    const int bc   = blockIdx.x >> 4;          // (b*CHAN + c), 0..255
    const int part = blockIdx.x & (SPLIT - 1); // 0..15

    const float* lrow = l + bc * W;
    const float* rrow = r + bc * W;
    for (int t = threadIdx.x; t < W; t += 256) {
        sl[t] = lrow[t];
        sr[t] = rrow[t];
    }
    __syncthreads();

    v4f* out4 = (v4f*)out + (size_t)bc * TILE4;
    const int kbeg = part * PART;

    for (int pass = 0; pass < PASSES; ++pass) {
        if (part != SPLIT - 1) {
            int k = kbeg + (int)threadIdx.x;
            #pragma unroll 5
            for (int n = 0; n < NFULL; ++n, k += 256) {
                int i  = k / W4;
                int j4 = k - i * W4;
                float rv = sr[i];
                v4f   lv = *(const v4f*)&sl[j4 * 4];
                v4f   o;
                o.x = fabsf(lv.x - rv);
                o.y = fabsf(lv.y - rv);
                o.z = fabsf(lv.z - rv);
                o.w = fabsf(lv.w - rv);
                out4[k] = o;
            }
        } else {
            for (int k = kbeg + (int)threadIdx.x; k < TILE4; k += 256) {
                int i  = k / W4;
                int j4 = k - i * W4;
                float rv = sr[i];
                v4f   lv = *(const v4f*)&sl[j4 * 4];
                v4f   o;
                o.x = fabsf(lv.x - rv);
                o.y = fabsf(lv.y - rv);
                o.z = fabsf(lv.z - rv);
                o.w = fabsf(lv.w - rv);
                out4[k] = o;
            }
        }
        asm volatile("" ::: "memory");   // keep every pass's stores
    }
}

extern "C" void kernel_launch(void* const* d_in, const int* in_sizes, int n_in,
                              void* d_out, int out_size, void* d_ws, size_t ws_size,
                              hipStream_t stream) {
    const float* l = (const float*)d_in[0];
    const float* r = (const float*)d_in[1];
    float* out = (float*)d_out;

    dim3 grid(BS * CHAN * SPLIT);   // 4096 blocks
    dim3 block(256);
    deltaLayer_57294863728910_kernel<<<grid, block, 0, stream>>>(l, r, out);
}